// Round 1
// baseline (928.175 us; speedup 1.0000x reference)
//
#include <hip/hip_runtime.h>

typedef _Float16 half8 __attribute__((ext_vector_type(8)));
typedef float    f32x4 __attribute__((ext_vector_type(4)));

#define NB  256
#define NH  512
#define NSQ 256
#define NSP 256

// ---------------------------------------------------------------------------
// Pre-pass: transpose + f32->f16 convert Q and P into MFMA-fragment-ordered
// arrays in the workspace. 3 jobs x 4096 blocks (one per (b, 32-h chunk)).
//   QAf [b][t(4)][kc(16)][w(4)][lane(64) x half8]  : phase-1 A fragments
//   PBf [b][kc(16)][nt(16)][lane x half8]          : phase-1 B fragments
//   PB2f[b][hc(16)][ks(8)][nt(2)][lane x half8]    : phase-2 B fragments
// Each array is 256 KB/batch = 64 MiB total; sum = 192 MiB of d_ws.
// All reads are full-64B-line scalar/vector loads; all writes are lane*16B
// contiguous (perfectly coalesced).
// ---------------------------------------------------------------------------
__global__ __launch_bounds__(256)
void prep_kernel(const float* __restrict__ Q, const float* __restrict__ P,
                 _Float16* __restrict__ QAf, _Float16* __restrict__ PBf,
                 _Float16* __restrict__ PB2f)
{
    const int tid  = threadIdx.x;
    const int w    = tid >> 6;
    const int lane = tid & 63;
    const int c    = lane & 15;
    const int g    = lane >> 4;
    const int id   = blockIdx.x & 4095;
    const int b    = id >> 4;
    const int kc   = id & 15;
    const int job  = blockIdx.x >> 12;

    if (job == 0) {
        // A fragments: value = Q[b][kc*32 + g*8 + j][t*64 + w*16 + c]
        const float* src = Q + (size_t)b * (NH * NSQ);
        _Float16* dstb = QAf + (size_t)b * 131072;
#pragma unroll
        for (int t = 0; t < 4; ++t) {
            half8 hv;
#pragma unroll
            for (int j = 0; j < 8; ++j)
                hv[j] = (_Float16)src[(kc*32 + g*8 + j) * NSQ + t*64 + w*16 + c];
            *(half8*)(dstb + ((size_t)((t*16 + kc)*4 + w))*512 + lane*8) = hv;
        }
    } else if (job == 1) {
        // phase-1 B fragments: value = P[b][kc*32 + g*8 + j][nt*16 + c]
        const float* src = P + (size_t)b * (NH * NSP);
        _Float16* dstb = PBf + (size_t)b * 131072;
#pragma unroll
        for (int i = 0; i < 4; ++i) {
            const int nt = w*4 + i;
            half8 hv;
#pragma unroll
            for (int j = 0; j < 8; ++j)
                hv[j] = (_Float16)src[(kc*32 + g*8 + j) * NSP + nt*16 + c];
            *(half8*)(dstb + ((size_t)(kc*16 + nt))*512 + lane*8) = hv;
        }
    } else {
        // phase-2 B fragments: value = P[b][hc*32 + nt*16 + c][ks*32 + g*8 + j]
        const float* src = P + (size_t)b * (NH * NSP);
        _Float16* dstb = PB2f + (size_t)b * 131072;
        const int hc = kc;
#pragma unroll
        for (int i = 0; i < 4; ++i) {
            const int f  = w*4 + i;
            const int ks = f >> 1;
            const int nt = f & 1;
            const float* s2 = src + (hc*32 + nt*16 + c) * NSP + ks*32 + g*8;
            f32x4 x0 = *(const f32x4*)s2;
            f32x4 x1 = *(const f32x4*)(s2 + 4);
            half8 hv;
#pragma unroll
            for (int l = 0; l < 4; ++l) { hv[l] = (_Float16)x0[l]; hv[4+l] = (_Float16)x1[l]; }
            *(half8*)(dstb + ((size_t)((hc*8 + ks)*2 + nt))*512 + lane*8) = hv;
        }
    }
}

// ---------------------------------------------------------------------------
// Main kernel: one block = (batch b, 64-row q-tile). 4 waves, ZERO barriers.
// Phase 1: S(64x256) via register-direct fragment loads from QAf/PBf.
// Softmax in registers (identical math/order to previous version).
// att transposed through wave-private LDS, subtiled [ks][row][32] (stride 80B)
// so phase-2 ds_read_b128 is bank-uniform.
// Phase 2: q~ via fragment loads from PB2f; epilogue stores directly from
// C-layout (4x64B fully-used segments per store instruction).
// ---------------------------------------------------------------------------
__global__ __launch_bounds__(256, 3)
void rmatch_main(const float* __restrict__ Q,
                 const _Float16* __restrict__ QAf,
                 const _Float16* __restrict__ PBf,
                 const _Float16* __restrict__ PB2f,
                 const int* __restrict__ QM, const int* __restrict__ PM,
                 float* __restrict__ out)
{
    __shared__ _Float16 att[8][64][40];   // 40 KB; [p-slab ks][q row][k-in-32], row stride 80B

    const int tid  = threadIdx.x;
    // XCD-bijective swizzle: the 4 q-tiles of a batch land on the same XCD
    const int lb   = (blockIdx.x & 7) * 128 + (blockIdx.x >> 3);
    const int b    = lb >> 2;
    const int t    = lb & 3;
    const int q0   = t << 6;
    const int w    = tid >> 6;
    const int lane = tid & 63;
    const int c    = lane & 15;
    const int g    = lane >> 4;

    f32x4 acc1[16];
#pragma unroll
    for (int nt = 0; nt < 16; ++nt) { f32x4 z = {0.f,0.f,0.f,0.f}; acc1[nt] = z; }

    // ---------------- phase 1: S = Q^T P, barrier-free fragment GEMM --------
    const _Float16* Ab = QAf + (size_t)b*131072 + (size_t)(t*64 + w)*512 + (size_t)lane*8;
    const _Float16* Bb = PBf + (size_t)b*131072 + (size_t)lane*8;
    for (int kc = 0; kc < 16; ++kc) {
        half8 av = *(const half8*)(Ab + kc*2048);
        const _Float16* bp = Bb + (size_t)kc*8192;
#pragma unroll
        for (int nt = 0; nt < 16; ++nt) {
            half8 bv = *(const half8*)(bp + nt*512);
            acc1[nt] = __builtin_amdgcn_mfma_f32_16x16x32_f16(av, bv, acc1[nt], 0, 0, 0);
        }
    }

    // ---------------- masked softmax over p, in registers -------------------
    // lane holds S[row = 16w + 4g + reg][p = nt*16 + c]
    {
        const int* qm = QM + b * NSQ + q0;
        const int* pm = PM + b * NSP;
        int pmv[16];
#pragma unroll
        for (int nt = 0; nt < 16; ++nt) pmv[nt] = pm[nt*16 + c];
#pragma unroll
        for (int reg = 0; reg < 4; ++reg) {
            const int row = 16*w + 4*g + reg;
            const int qmv = qm[row];
            float mx = -3.0e38f;
#pragma unroll
            for (int nt = 0; nt < 16; ++nt) {
                float v = acc1[nt][reg];
                if (qmv & pmv[nt]) v += -1000000.0f;   // NEG_INF mask
                acc1[nt][reg] = v;
                mx = fmaxf(mx, v);
            }
#pragma unroll
            for (int xm = 1; xm < 16; xm <<= 1)
                mx = fmaxf(mx, __shfl_xor(mx, xm, 64));
            float s = 0.f;
#pragma unroll
            for (int nt = 0; nt < 16; ++nt) {
                float e = __expf(acc1[nt][reg] - mx);
                acc1[nt][reg] = e;
                s += e;
            }
#pragma unroll
            for (int xm = 1; xm < 16; xm <<= 1)
                s += __shfl_xor(s, xm, 64);
            const float inv = 1.0f / s;
#pragma unroll
            for (int nt = 0; nt < 16; ++nt)
                att[nt >> 1][row][(nt & 1)*16 + c] = (_Float16)(acc1[nt][reg] * inv);
        }
    }
    // NO __syncthreads: wave w wrote rows 16w..16w+15 and reads only those.

    // ---------------- phase 2: q~ = att @ P^T, barrier-free -----------------
    const _Float16* B2 = PB2f + (size_t)b*131072 + (size_t)lane*8;
    const float*    Qg = Q + (size_t)b * (NH * NSQ);

    for (int hc = 0; hc < 16; ++hc) {
        // prefetch q_t (f32, exact) before the MFMA chain hides the latency
        float qt[2][4];
#pragma unroll
        for (int nt = 0; nt < 2; ++nt)
#pragma unroll
            for (int reg = 0; reg < 4; ++reg)
                qt[nt][reg] = Qg[(hc*32 + nt*16 + c) * NSQ + q0 + 16*w + 4*g + reg];

        f32x4 acc2[2];
        { f32x4 z = {0.f,0.f,0.f,0.f}; acc2[0] = z; acc2[1] = z; }
#pragma unroll
        for (int ks = 0; ks < 8; ++ks) {
            half8 av2 = *(const half8*)&att[ks][16*w + c][g*8];
#pragma unroll
            for (int nt = 0; nt < 2; ++nt) {
                half8 bv = *(const half8*)(B2 + (size_t)(hc*16 + ks*2 + nt)*512);
                acc2[nt] = __builtin_amdgcn_mfma_f32_16x16x32_f16(av2, bv, acc2[nt], 0, 0, 0);
            }
        }
        // direct epilogue from C-layout: row = 16w+4g+reg, col h = hc*32+nt*16+c
#pragma unroll
        for (int nt = 0; nt < 2; ++nt)
#pragma unroll
            for (int reg = 0; reg < 4; ++reg) {
                const int q  = q0 + 16*w + 4*g + reg;
                const int h  = hc*32 + nt*16 + c;
                const float qv = qt[nt][reg];
                const float tv = acc2[nt][reg];
                float* ob = out + (size_t)(b * NSQ + q) * 2048 + h;
                ob[0]    = qv;
                ob[512]  = tv;
                ob[1024] = qv - tv;
                ob[1536] = qv * tv;
            }
    }
}

// ---------------------------------------------------------------------------
// Fallback (previous kernel) in case ws_size is ever too small.
// ---------------------------------------------------------------------------
__global__ __launch_bounds__(256, 2)
void rmatch_kernel(const float* __restrict__ Q, const float* __restrict__ P,
                   const int* __restrict__ QM, const int* __restrict__ PM,
                   float* __restrict__ out)
{
    __shared__ union {
        struct { _Float16 A[64][40];  _Float16 Bm[256][40]; } p1;
        struct { _Float16 P2[32][264]; } p2;
    } stg;
    __shared__ _Float16 att[64][264];
    __shared__ float    qtl[64][36];

    const int tid  = threadIdx.x;
    const int b    = blockIdx.x >> 2;
    const int q0   = (blockIdx.x & 3) << 6;
    const int w    = tid >> 6;
    const int lane = tid & 63;
    const int c    = lane & 15;
    const int g    = lane >> 4;

    const float* Qg = Q + (size_t)b * NH * NSQ;
    const float* Pg = P + (size_t)b * NH * NSP;

    f32x4 acc1[16];
#pragma unroll
    for (int nt = 0; nt < 16; ++nt) { f32x4 z = {0.f,0.f,0.f,0.f}; acc1[nt] = z; }

    const int aL = tid & 63;
    const int aB = tid >> 6;

    for (int kc = 0; kc < 16; ++kc) {
        const int h0 = kc * 32;
        {
            half8 hv;
#pragma unroll
            for (int j = 0; j < 8; ++j)
                hv[j] = (_Float16)Qg[(h0 + aB*8 + j) * NSQ + q0 + aL];
            *(half8*)&stg.p1.A[aL][aB*8] = hv;
        }
#pragma unroll
        for (int it = 0; it < 4; ++it) {
            half8 hv;
#pragma unroll
            for (int j = 0; j < 8; ++j)
                hv[j] = (_Float16)Pg[(h0 + it*8 + j) * NSP + tid];
            *(half8*)&stg.p1.Bm[tid][it*8] = hv;
        }
        __syncthreads();
        half8 av = *(const half8*)&stg.p1.A[16*w + c][g*8];
#pragma unroll
        for (int nt = 0; nt < 16; ++nt) {
            half8 bv = *(const half8*)&stg.p1.Bm[nt*16 + c][g*8];
            acc1[nt] = __builtin_amdgcn_mfma_f32_16x16x32_f16(av, bv, acc1[nt], 0, 0, 0);
        }
        __syncthreads();
    }

    {
        const int* qm = QM + b * NSQ + q0;
        const int* pm = PM + b * NSP;
        int pmv[16];
#pragma unroll
        for (int nt = 0; nt < 16; ++nt) pmv[nt] = pm[nt*16 + c];
#pragma unroll
        for (int reg = 0; reg < 4; ++reg) {
            const int row = 16*w + 4*g + reg;
            const int qmv = qm[row];
            float mx = -3.0e38f;
#pragma unroll
            for (int nt = 0; nt < 16; ++nt) {
                float v = acc1[nt][reg];
                if (qmv & pmv[nt]) v += -1000000.0f;
                acc1[nt][reg] = v;
                mx = fmaxf(mx, v);
            }
#pragma unroll
            for (int xm = 1; xm < 16; xm <<= 1)
                mx = fmaxf(mx, __shfl_xor(mx, xm, 64));
            float s = 0.f;
#pragma unroll
            for (int nt = 0; nt < 16; ++nt) {
                float e = __expf(acc1[nt][reg] - mx);
                acc1[nt][reg] = e;
                s += e;
            }
#pragma unroll
            for (int xm = 1; xm < 16; xm <<= 1)
                s += __shfl_xor(s, xm, 64);
            const float inv = 1.0f / s;
#pragma unroll
            for (int nt = 0; nt < 16; ++nt)
                att[row][nt*16 + c] = (_Float16)(acc1[nt][reg] * inv);
        }
    }
    __syncthreads();

    for (int hc = 0; hc < 16; ++hc) {
        const int h1 = hc * 32;
#pragma unroll
        for (int it = 0; it < 4; ++it) {
            const int tk  = tid + 256*it;
            const int row = tk >> 5;
            const int c8  = tk & 31;
            const float* src = &Pg[(h1 + row) * NSP + c8*8];
            f32x4 x0 = *(const f32x4*)src;
            f32x4 x1 = *(const f32x4*)(src + 4);
            half8 hv;
#pragma unroll
            for (int l = 0; l < 4; ++l) { hv[l] = (_Float16)x0[l]; hv[4+l] = (_Float16)x1[l]; }
            *(half8*)&stg.p2.P2[row][c8*8] = hv;
        }
        __syncthreads();

        f32x4 acc2[2];
        { f32x4 z = {0.f,0.f,0.f,0.f}; acc2[0] = z; acc2[1] = z; }
#pragma unroll
        for (int ks = 0; ks < 8; ++ks) {
            half8 av = *(const half8*)&att[16*w + c][ks*32 + g*8];
#pragma unroll
            for (int nt = 0; nt < 2; ++nt) {
                half8 bv = *(const half8*)&stg.p2.P2[nt*16 + c][ks*32 + g*8];
                acc2[nt] = __builtin_amdgcn_mfma_f32_16x16x32_f16(av, bv, acc2[nt], 0, 0, 0);
            }
        }
#pragma unroll
        for (int nt = 0; nt < 2; ++nt)
#pragma unroll
            for (int reg = 0; reg < 4; ++reg)
                qtl[16*w + 4*g + reg][nt*16 + c] = acc2[nt][reg];
        __syncthreads();

        {
            const int qq = tid >> 2, hg = tid & 3;
            float* ob = out + ((size_t)(b * NSQ + q0 + qq)) * 2048 + h1;
#pragma unroll
            for (int j = 0; j < 2; ++j) {
                const int h4 = hg + 4*j;
                f32x4 t4 = *(const f32x4*)&qtl[qq][h4*4];
                f32x4 qtv;
#pragma unroll
                for (int l = 0; l < 4; ++l)
                    qtv[l] = Qg[(h1 + h4*4 + l) * NSQ + q0 + qq];
                f32x4 df = qtv - t4;
                f32x4 pr = qtv * t4;
                *(f32x4*)&ob[        h4*4] = qtv;
                *(f32x4*)&ob[ 512  + h4*4] = t4;
                *(f32x4*)&ob[1024  + h4*4] = df;
                *(f32x4*)&ob[1536  + h4*4] = pr;
            }
        }
        __syncthreads();
    }
}

extern "C" void kernel_launch(void* const* d_in, const int* in_sizes, int n_in,
                              void* d_out, int out_size, void* d_ws, size_t ws_size,
                              hipStream_t stream)
{
    const float* Q  = (const float*)d_in[0];
    const float* P  = (const float*)d_in[1];
    const int*   QM = (const int*)d_in[2];
    const int*   PM = (const int*)d_in[3];
    float* o = (float*)d_out;

    const size_t need = (size_t)3 * 67108864;  // 192 MiB of f16 fragments
    if (ws_size >= need && d_ws != nullptr) {
        _Float16* QAf  = (_Float16*)d_ws;
        _Float16* PBf  = QAf + 33554432;   // 64 MiB / 2B
        _Float16* PB2f = PBf + 33554432;
        prep_kernel<<<dim3(3 * 4096), dim3(256), 0, stream>>>(Q, P, QAf, PBf, PB2f);
        rmatch_main<<<dim3(NB * 4), dim3(256), 0, stream>>>(Q, QAf, PBf, PB2f, QM, PM, o);
    } else {
        rmatch_kernel<<<dim3(NB * 4), dim3(256), 0, stream>>>(Q, P, QM, PM, o);
    }
}